// Round 1
// baseline (834.375 us; speedup 1.0000x reference)
//
#include <hip/hip_runtime.h>

// Problem constants
constexpr int B = 8;
constexpr int N = 2048;
constexpr int D = 256;
constexpr int L = 2;

// ---------------------------------------------------------------------------
// Kernel 1: rdenom[b,n] = 1 / (sum_k adj[b,n,k] + 1)
// One wave (64 lanes) per row; float4 loads; shuffle reduce.
// ---------------------------------------------------------------------------
__global__ __launch_bounds__(256)
void denom_kernel(const float* __restrict__ adj, float* __restrict__ rdenom) {
    const int wave = threadIdx.x >> 6;
    const int lane = threadIdx.x & 63;
    const int row  = blockIdx.x * 4 + wave;          // [0, B*N)
    const float4* p = (const float4*)(adj + (size_t)row * N);
    float s = 0.f;
    #pragma unroll
    for (int i = 0; i < N / 4 / 64; ++i) {           // 512 float4 / 64 lanes = 8
        float4 v = p[lane + i * 64];
        s += (v.x + v.y) + (v.z + v.w);
    }
    #pragma unroll
    for (int off = 32; off > 0; off >>= 1) s += __shfl_down(s, off);
    if (lane == 0) rdenom[row] = 1.0f / (s + 1.0f);
}

// ---------------------------------------------------------------------------
// Kernel 2: fused weight GEMM.  X: [M=B*N, K=D] row-major.
// blockIdx.z == 0: out = X @ Wr^T + br   (Wr stored [D][D] = [m][k])
// blockIdx.z == 1: out = X @ W0^T + b0
// 64x64 tile, BK=16, 256 threads, 4x4 micro-tile.
// ---------------------------------------------------------------------------
__global__ __launch_bounds__(256)
void xw_kernel(const float* __restrict__ X,
               const float* __restrict__ Wr, const float* __restrict__ br,
               const float* __restrict__ W0, const float* __restrict__ b0,
               float* __restrict__ outWr, float* __restrict__ outW0) {
    constexpr int K = D;
    const float* Wmat = (blockIdx.z == 0) ? Wr : W0;
    const float* bias = (blockIdx.z == 0) ? br : b0;
    float*       out  = (blockIdx.z == 0) ? outWr : outW0;

    __shared__ float As[16][68];   // pad 68: float4-aligned reads, 2-way-bank max
    __shared__ float Bs[16][68];

    const int t  = threadIdx.x;
    const int m0 = blockIdx.y * 64;
    const int n0 = blockIdx.x * 64;

    const int lr = t >> 2;           // 0..63 tile row
    const int lc = (t & 3) * 4;      // 0,4,8,12 k-offset

    const int ty = (t >> 4) * 4;     // acc row base
    const int tx = (t & 15) * 4;     // acc col base

    float acc[4][4] = {};

    for (int k0 = 0; k0 < K; k0 += 16) {
        const float4 av = *(const float4*)(X    + (size_t)(m0 + lr) * K + k0 + lc);
        const float4 bv = *(const float4*)(Wmat + (size_t)(n0 + lr) * K + k0 + lc);
        __syncthreads();
        As[lc + 0][lr] = av.x; As[lc + 1][lr] = av.y;
        As[lc + 2][lr] = av.z; As[lc + 3][lr] = av.w;
        Bs[lc + 0][lr] = bv.x; Bs[lc + 1][lr] = bv.y;
        Bs[lc + 2][lr] = bv.z; Bs[lc + 3][lr] = bv.w;
        __syncthreads();
        #pragma unroll
        for (int k = 0; k < 16; ++k) {
            const float4 a4 = *(const float4*)&As[k][ty];
            const float4 b4 = *(const float4*)&Bs[k][tx];
            const float a[4] = {a4.x, a4.y, a4.z, a4.w};
            const float b[4] = {b4.x, b4.y, b4.z, b4.w};
            #pragma unroll
            for (int i = 0; i < 4; ++i)
                #pragma unroll
                for (int j = 0; j < 4; ++j)
                    acc[i][j] = fmaf(a[i], b[j], acc[i][j]);
        }
    }
    #pragma unroll
    for (int i = 0; i < 4; ++i) {
        const size_t rowBase = (size_t)(m0 + ty + i) * D + n0;
        #pragma unroll
        for (int j = 0; j < 4; ++j)
            out[rowBase + tx + j] = acc[i][j] + bias[n0 + tx + j];
    }
}

// ---------------------------------------------------------------------------
// Kernel 3: per-batch adj GEMM + fused epilogue.
// C[b,m,n] = sum_k adj[b,m,k] * xWr[b,k,n]
// x_new = relu((C + xW0) * rdenom)   [+ nodes if final layer]
// ---------------------------------------------------------------------------
__global__ __launch_bounds__(256)
void adj_gemm_kernel(const float* __restrict__ adj,
                     const float* __restrict__ xWr,
                     const float* __restrict__ xW0,
                     const float* __restrict__ rdenom,
                     const float* __restrict__ nodes,   // nullptr if not final
                     float* __restrict__ out) {
    const int b = blockIdx.z;
    const float* A  = adj + (size_t)b * N * N;
    const float* Bm = xWr + (size_t)b * N * D;

    __shared__ float As[16][68];
    __shared__ float Bs[16][68];

    const int t  = threadIdx.x;
    const int m0 = blockIdx.y * 64;
    const int n0 = blockIdx.x * 64;

    const int lr = t >> 2;           // A tile row 0..63
    const int lc = (t & 3) * 4;      // A k-offset

    const int bk = t >> 4;           // B tile k-row 0..15
    const int bc = (t & 15) * 4;     // B col 0..60

    const int ty = (t >> 4) * 4;
    const int tx = (t & 15) * 4;

    float acc[4][4] = {};

    for (int k0 = 0; k0 < N; k0 += 16) {
        const float4 av = *(const float4*)(A  + (size_t)(m0 + lr) * N + k0 + lc);
        const float4 bv = *(const float4*)(Bm + (size_t)(k0 + bk) * D + n0 + bc);
        __syncthreads();
        As[lc + 0][lr] = av.x; As[lc + 1][lr] = av.y;
        As[lc + 2][lr] = av.z; As[lc + 3][lr] = av.w;
        *(float4*)&Bs[bk][bc] = bv;
        __syncthreads();
        #pragma unroll
        for (int k = 0; k < 16; ++k) {
            const float4 a4 = *(const float4*)&As[k][ty];
            const float4 b4 = *(const float4*)&Bs[k][tx];
            const float a[4] = {a4.x, a4.y, a4.z, a4.w};
            const float b[4] = {b4.x, b4.y, b4.z, b4.w};
            #pragma unroll
            for (int i = 0; i < 4; ++i)
                #pragma unroll
                for (int j = 0; j < 4; ++j)
                    acc[i][j] = fmaf(a[i], b[j], acc[i][j]);
        }
    }

    const size_t base = (size_t)b * N * D;
    #pragma unroll
    for (int i = 0; i < 4; ++i) {
        const int m = m0 + ty + i;
        const float rd = rdenom[b * N + m];
        const size_t rowBase = base + (size_t)m * D + n0;
        #pragma unroll
        for (int j = 0; j < 4; ++j) {
            float v = (acc[i][j] + xW0[rowBase + tx + j]) * rd;
            v = fmaxf(v, 0.0f);
            if (nodes) v += nodes[rowBase + tx + j];
            out[rowBase + tx + j] = v;
        }
    }
}

// ---------------------------------------------------------------------------
extern "C" void kernel_launch(void* const* d_in, const int* in_sizes, int n_in,
                              void* d_out, int out_size, void* d_ws, size_t ws_size,
                              hipStream_t stream) {
    const float* nodes = (const float*)d_in[0];   // [B,N,D]
    const float* adj   = (const float*)d_in[1];   // [B,N,N]
    const float* W0_w  = (const float*)d_in[2];   // [L,D,D]
    const float* W0_b  = (const float*)d_in[3];   // [L,D]
    const float* Wr_w  = (const float*)d_in[4];   // [L,D,D]
    const float* Wr_b  = (const float*)d_in[5];   // [L,D]
    float* out = (float*)d_out;

    float* rdenom = (float*)d_ws;                         // B*N
    float* x1     = rdenom + (size_t)B * N;               // B*N*D
    float* xWr    = x1     + (size_t)B * N * D;           // B*N*D
    float* xW0    = xWr    + (size_t)B * N * D;           // B*N*D

    denom_kernel<<<dim3(B * N / 4), 256, 0, stream>>>(adj, rdenom);

    const float* x = nodes;
    for (int l = 0; l < L; ++l) {
        xw_kernel<<<dim3(D / 64, B * N / 64, 2), 256, 0, stream>>>(
            x,
            Wr_w + (size_t)l * D * D, Wr_b + (size_t)l * D,
            W0_w + (size_t)l * D * D, W0_b + (size_t)l * D,
            xWr, xW0);
        const bool fin = (l == L - 1);
        adj_gemm_kernel<<<dim3(D / 64, N / 64, B), 256, 0, stream>>>(
            adj, xWr, xW0, rdenom,
            fin ? nodes : nullptr,
            fin ? out : x1);
        x = x1;
    }
}

// Round 2
// 484.422 us; speedup vs baseline: 1.7224x; 1.7224x over previous
//
#include <hip/hip_runtime.h>

// Problem constants
constexpr int B = 8;
constexpr int N = 2048;
constexpr int D = 256;
constexpr int L = 2;

typedef __bf16 bf16x8 __attribute__((ext_vector_type(8)));
typedef float  f32x4  __attribute__((ext_vector_type(4)));

static __device__ __forceinline__ unsigned short f2bf(float f) {
    union { float f; unsigned u; } v; v.f = f;
    unsigned r = v.u + 0x7fffu + ((v.u >> 16) & 1u);   // RNE
    return (unsigned short)(r >> 16);
}

static __device__ __forceinline__ void gload16(const void* g, void* l) {
    __builtin_amdgcn_global_load_lds(
        (__attribute__((address_space(1))) void*)(g),
        (__attribute__((address_space(3))) void*)(l),
        16, 0, 0);
}

// ---------------------------------------------------------------------------
// Kernel 1: rdenom[b,n] = 1/(rowsum(adj)+1)  AND  adj -> bf16 copy.
// One wave per row; float4 loads; shuffle reduce; ushort4 bf16 stores.
// ---------------------------------------------------------------------------
__global__ __launch_bounds__(256)
void denom_cast_kernel(const float* __restrict__ adj,
                       unsigned short* __restrict__ adjb,
                       float* __restrict__ rdenom) {
    const int wave = threadIdx.x >> 6;
    const int lane = threadIdx.x & 63;
    const int row  = blockIdx.x * 4 + wave;          // [0, B*N)
    const float4* p = (const float4*)(adj + (size_t)row * N);
    ushort4* q = (ushort4*)(adjb + (size_t)row * N);
    float s = 0.f;
    #pragma unroll
    for (int i = 0; i < 8; ++i) {
        float4 v = p[lane + i * 64];
        s += (v.x + v.y) + (v.z + v.w);
        ushort4 o;
        o.x = f2bf(v.x); o.y = f2bf(v.y); o.z = f2bf(v.z); o.w = f2bf(v.w);
        q[lane + i * 64] = o;
    }
    #pragma unroll
    for (int off = 32; off > 0; off >>= 1) s += __shfl_down(s, off);
    if (lane == 0) rdenom[row] = 1.0f / (s + 1.0f);
}

// ---------------------------------------------------------------------------
// Kernel 2: fused weight GEMM.  X: [M=B*N, K=D] row-major fp32.
// z==0: xWrT[b][d][n] = bf16( X@Wr^T + br )   (TRANSPOSED, bf16 for MFMA B-op)
// z==1: xW0 [b][n][d] = fp32( X@W0^T + b0 )
// 64x64 tile, BK=16, 256 threads, 4x4 micro-tile.
// ---------------------------------------------------------------------------
__global__ __launch_bounds__(256)
void xw_kernel(const float* __restrict__ X,
               const float* __restrict__ Wr, const float* __restrict__ br,
               const float* __restrict__ W0, const float* __restrict__ b0,
               unsigned short* __restrict__ xWrT, float* __restrict__ xW0) {
    constexpr int K = D;
    const float* Wmat = (blockIdx.z == 0) ? Wr : W0;
    const float* bias = (blockIdx.z == 0) ? br : b0;

    __shared__ float As[16][68];
    __shared__ float Bs[16][68];

    const int t  = threadIdx.x;
    const int m0 = blockIdx.y * 64;
    const int n0 = blockIdx.x * 64;

    const int lr = t >> 2;           // 0..63 tile row
    const int lc = (t & 3) * 4;      // 0,4,8,12 k-offset

    const int ty = (t >> 4) * 4;     // acc row base
    const int tx = (t & 15) * 4;     // acc col base

    float acc[4][4] = {};

    for (int k0 = 0; k0 < K; k0 += 16) {
        const float4 av = *(const float4*)(X    + (size_t)(m0 + lr) * K + k0 + lc);
        const float4 bv = *(const float4*)(Wmat + (size_t)(n0 + lr) * K + k0 + lc);
        __syncthreads();
        As[lc + 0][lr] = av.x; As[lc + 1][lr] = av.y;
        As[lc + 2][lr] = av.z; As[lc + 3][lr] = av.w;
        Bs[lc + 0][lr] = bv.x; Bs[lc + 1][lr] = bv.y;
        Bs[lc + 2][lr] = bv.z; Bs[lc + 3][lr] = bv.w;
        __syncthreads();
        #pragma unroll
        for (int k = 0; k < 16; ++k) {
            const float4 a4 = *(const float4*)&As[k][ty];
            const float4 b4 = *(const float4*)&Bs[k][tx];
            const float a[4] = {a4.x, a4.y, a4.z, a4.w};
            const float b[4] = {b4.x, b4.y, b4.z, b4.w};
            #pragma unroll
            for (int i = 0; i < 4; ++i)
                #pragma unroll
                for (int j = 0; j < 4; ++j)
                    acc[i][j] = fmaf(a[i], b[j], acc[i][j]);
        }
    }

    if (blockIdx.z == 0) {
        // transposed bf16 store: xWrT[b][d][n], pack 4 consecutive n as ushort4
        const int b    = m0 >> 11;        // m0 / N
        const int mloc = m0 & (N - 1);
        #pragma unroll
        for (int j = 0; j < 4; ++j) {
            const float bj = bias[n0 + tx + j];
            ushort4 o;
            o.x = f2bf(acc[0][j] + bj);
            o.y = f2bf(acc[1][j] + bj);
            o.z = f2bf(acc[2][j] + bj);
            o.w = f2bf(acc[3][j] + bj);
            *(ushort4*)(xWrT + ((size_t)b * D + (n0 + tx + j)) * N + mloc + ty) = o;
        }
    } else {
        #pragma unroll
        for (int i = 0; i < 4; ++i) {
            const size_t rowBase = (size_t)(m0 + ty + i) * D + n0;
            #pragma unroll
            for (int j = 0; j < 4; ++j)
                xW0[rowBase + tx + j] = acc[i][j] + bias[n0 + tx + j];
        }
    }
}

// ---------------------------------------------------------------------------
// Kernel 3: MFMA adj GEMM + fused epilogue.
// C[b,m,d] = sum_k adjb[b,m,k] * xWrT[b,d,k]      (bf16 x bf16 -> fp32)
// out = relu((C + xW0) * rdenom)   [+ nodes if final layer]
// 128x128 tile, BK=32, 4 waves (2x2), 16x16x32 MFMA, fragment-ordered LDS
// staged via global_load_lds width=16 (dest = base + lane*16).
// ---------------------------------------------------------------------------
__global__ __launch_bounds__(256)
void adj_mfma_kernel(const unsigned short* __restrict__ adjb,   // [B][N][N] bf16
                     const unsigned short* __restrict__ xWrT,   // [B][D][N] bf16
                     const float* __restrict__ xW0,             // [B][N][D]
                     const float* __restrict__ rdenom,          // [B][N]
                     const float* __restrict__ nodes,           // null if not final
                     float* __restrict__ out) {                 // [B][N][D]
    __shared__ unsigned short As[8 * 512];   // 8 frags x 1024 B (16m x 32k bf16)
    __shared__ unsigned short Bs[8 * 512];

    const int b    = blockIdx.z;
    const int n0   = blockIdx.x * 128;   // over D
    const int m0   = blockIdx.y * 128;   // over N
    const int t    = threadIdx.x;
    const int w    = t >> 6;             // wave 0..3
    const int lane = t & 63;
    const int wm   = (w & 1) * 64;
    const int wn   = (w >> 1) * 64;
    const int lrow = lane & 15;          // row within frag
    const int lk   = (lane >> 4) * 8;    // k offset within frag

    const unsigned short* Ab = adjb + (size_t)b * N * N;
    const unsigned short* Bb = xWrT + (size_t)b * D * N;

    // wave w stages A frags {2w,2w+1} and B frags {2w,2w+1}
    const unsigned short* gA0 = Ab + (size_t)(m0 + (2 * w + 0) * 16 + lrow) * N + lk;
    const unsigned short* gA1 = Ab + (size_t)(m0 + (2 * w + 1) * 16 + lrow) * N + lk;
    const unsigned short* gB0 = Bb + (size_t)(n0 + (2 * w + 0) * 16 + lrow) * N + lk;
    const unsigned short* gB1 = Bb + (size_t)(n0 + (2 * w + 1) * 16 + lrow) * N + lk;

    f32x4 acc[4][4];
    const f32x4 zero = {0.f, 0.f, 0.f, 0.f};
    #pragma unroll
    for (int i = 0; i < 4; ++i)
        #pragma unroll
        for (int j = 0; j < 4; ++j) acc[i][j] = zero;

    for (int k0 = 0; k0 < N; k0 += 32) {
        __syncthreads();   // prior iteration's reads done before overwrite
        gload16(gA0 + k0, &As[(2 * w + 0) * 512]);
        gload16(gA1 + k0, &As[(2 * w + 1) * 512]);
        gload16(gB0 + k0, &Bs[(2 * w + 0) * 512]);
        gload16(gB1 + k0, &Bs[(2 * w + 1) * 512]);
        __syncthreads();   // vmcnt(0) drain + barrier

        bf16x8 a[4], bb[4];
        #pragma unroll
        for (int i = 0; i < 4; ++i) {
            a[i]  = *(const bf16x8*)&As[((w & 1) * 4 + i) * 512 + lane * 8];
            bb[i] = *(const bf16x8*)&Bs[((w >> 1) * 4 + i) * 512 + lane * 8];
        }
        #pragma unroll
        for (int i = 0; i < 4; ++i)
            #pragma unroll
            for (int j = 0; j < 4; ++j)
                acc[i][j] = __builtin_amdgcn_mfma_f32_16x16x32_bf16(
                    a[i], bb[j], acc[i][j], 0, 0, 0);
    }

    // Epilogue: C/D layout col=lane&15, row=(lane>>4)*4+reg
    const float* xW0b = xW0 + (size_t)b * N * D;
    float*       outb = out + (size_t)b * N * D;
    const float* ndb  = nodes ? nodes + (size_t)b * N * D : nullptr;
    const int col  = lane & 15;
    const int quad = lane >> 4;
    #pragma unroll
    for (int i = 0; i < 4; ++i) {
        const int mBase = m0 + wm + i * 16 + quad * 4;
        #pragma unroll
        for (int r = 0; r < 4; ++r) {
            const int m = mBase + r;
            const float rd = rdenom[b * N + m];
            const size_t rowOff = (size_t)m * D;
            #pragma unroll
            for (int j = 0; j < 4; ++j) {
                const int d = n0 + wn + j * 16 + col;
                float v = (acc[i][j][r] + xW0b[rowOff + d]) * rd;
                v = fmaxf(v, 0.f);
                if (ndb) v += ndb[rowOff + d];
                outb[rowOff + d] = v;
            }
        }
    }
}

// ---------------------------------------------------------------------------
extern "C" void kernel_launch(void* const* d_in, const int* in_sizes, int n_in,
                              void* d_out, int out_size, void* d_ws, size_t ws_size,
                              hipStream_t stream) {
    const float* nodes = (const float*)d_in[0];   // [B,N,D]
    const float* adj   = (const float*)d_in[1];   // [B,N,N]
    const float* W0_w  = (const float*)d_in[2];   // [L,D,D]
    const float* W0_b  = (const float*)d_in[3];   // [L,D]
    const float* Wr_w  = (const float*)d_in[4];   // [L,D,D]
    const float* Wr_b  = (const float*)d_in[5];   // [L,D]
    float* out = (float*)d_out;

    // workspace layout (~109 MB)
    unsigned short* adjb = (unsigned short*)d_ws;            // B*N*N bf16 (64 MB)
    unsigned short* xWrT = adjb + (size_t)B * N * N;         // B*D*N bf16 (8 MB)
    float* xW0 = (float*)(xWrT + (size_t)B * D * N);         // B*N*D fp32 (16 MB)
    float* x1  = xW0 + (size_t)B * N * D;                    // B*N*D fp32 (16 MB)
    float* rdenom = x1 + (size_t)B * N * D;                  // B*N

    denom_cast_kernel<<<dim3(B * N / 4), 256, 0, stream>>>(adj, adjb, rdenom);

    const float* x = nodes;
    for (int l = 0; l < L; ++l) {
        xw_kernel<<<dim3(D / 64, B * N / 64, 2), 256, 0, stream>>>(
            x,
            Wr_w + (size_t)l * D * D, Wr_b + (size_t)l * D,
            W0_w + (size_t)l * D * D, W0_b + (size_t)l * D,
            xWrT, xW0);
        const bool fin = (l == L - 1);
        adj_mfma_kernel<<<dim3(D / 128, N / 128, B), 256, 0, stream>>>(
            adjb, xWrT, xW0, rdenom,
            fin ? nodes : nullptr,
            fin ? out : x1);
        x = x1;
    }
}

// Round 3
// 403.784 us; speedup vs baseline: 2.0664x; 1.1997x over previous
//
#include <hip/hip_runtime.h>

// Problem constants
constexpr int B = 8;
constexpr int N = 2048;
constexpr int D = 256;
constexpr int L = 2;
constexpr int M = B * N;   // 16384

typedef __bf16 bf16x8 __attribute__((ext_vector_type(8)));
typedef float  f32x4  __attribute__((ext_vector_type(4)));

static __device__ __forceinline__ unsigned short f2bf(float f) {
    union { float f; unsigned u; } v; v.f = f;
    unsigned r = v.u + 0x7fffu + ((v.u >> 16) & 1u);   // RNE
    return (unsigned short)(r >> 16);
}

static __device__ __forceinline__ void gload16(const void* g, void* l) {
    __builtin_amdgcn_global_load_lds(
        (__attribute__((address_space(1))) void*)(g),
        (__attribute__((address_space(3))) void*)(l),
        16, 0, 0);
}

// ---------------------------------------------------------------------------
// Kernel 1: rowsum[b,n] = sum_k adj[b,n,k]; rdenom = 1/(rowsum+1); adj -> bf16.
// One wave per row; float4 loads; shuffle reduce; ushort4 bf16 stores.
// ---------------------------------------------------------------------------
__global__ __launch_bounds__(256)
void denom_cast_kernel(const float* __restrict__ adj,
                       unsigned short* __restrict__ adjb,
                       float* __restrict__ rdenom,
                       float* __restrict__ rowsum) {
    const int wave = threadIdx.x >> 6;
    const int lane = threadIdx.x & 63;
    const int row  = blockIdx.x * 4 + wave;          // [0, B*N)
    const float4* p = (const float4*)(adj + (size_t)row * N);
    ushort4* q = (ushort4*)(adjb + (size_t)row * N);
    float s = 0.f;
    #pragma unroll
    for (int i = 0; i < 8; ++i) {
        float4 v = p[lane + i * 64];
        s += (v.x + v.y) + (v.z + v.w);
        ushort4 o;
        o.x = f2bf(v.x); o.y = f2bf(v.y); o.z = f2bf(v.z); o.w = f2bf(v.w);
        q[lane + i * 64] = o;
    }
    #pragma unroll
    for (int off = 32; off > 0; off >>= 1) s += __shfl_down(s, off);
    if (lane == 0) {
        rowsum[row] = s;
        rdenom[row] = 1.0f / (s + 1.0f);
    }
}

// ---------------------------------------------------------------------------
// Kernel 2: nodes fp32 [b][n][d] -> nodesbf bf16 [b][n][d] AND nodesT [b][d][n].
// 64x64 tiles, transpose through LDS.
// ---------------------------------------------------------------------------
__global__ __launch_bounds__(256)
void cast_nodes_kernel(const float* __restrict__ nodes,
                       unsigned short* __restrict__ nodesbf,
                       unsigned short* __restrict__ nodesT) {
    __shared__ unsigned short T[64][68];   // 68*2=136 B row stride, 8B-aligned
    const int b  = blockIdx.z;
    const int n0 = blockIdx.y * 64;
    const int d0 = blockIdx.x * 64;
    const int t  = threadIdx.x;
    const int r  = t >> 2;                 // 0..63
    const int c4 = t & 3;                  // 0..3
    const float*    src = nodes   + ((size_t)b * N + n0) * D + d0;
    unsigned short* dst = nodesbf + ((size_t)b * N + n0) * D + d0;
    #pragma unroll
    for (int rep = 0; rep < 4; ++rep) {
        const int fc = c4 + rep * 4;       // float4 col 0..15
        float4 v = *(const float4*)(src + (size_t)r * D + fc * 4);
        ushort4 o;
        o.x = f2bf(v.x); o.y = f2bf(v.y); o.z = f2bf(v.z); o.w = f2bf(v.w);
        *(ushort4*)(dst + (size_t)r * D + fc * 4) = o;
        *(ushort4*)&T[r][fc * 4] = o;
    }
    __syncthreads();
    unsigned short* dstT = nodesT + ((size_t)b * D + d0) * N + n0;
    #pragma unroll
    for (int rep = 0; rep < 4; ++rep) {
        const int nc = c4 + rep * 4;       // n-chunk 0..15
        ushort4 o;
        o.x = T[nc * 4 + 0][r];
        o.y = T[nc * 4 + 1][r];
        o.z = T[nc * 4 + 2][r];
        o.w = T[nc * 4 + 3][r];
        *(ushort4*)(dstT + (size_t)r * N + nc * 4) = o;   // row d0+r, col n0+nc*4
    }
}

// ---------------------------------------------------------------------------
// Kernel 3: cast both weight tensors [L][D][D] fp32 -> bf16.
// ---------------------------------------------------------------------------
__global__ __launch_bounds__(256)
void cast_w_kernel(const float* __restrict__ W0_w, const float* __restrict__ Wr_w,
                   unsigned short* __restrict__ W0b, unsigned short* __restrict__ Wrb) {
    const int i = blockIdx.x * 256 + threadIdx.x;   // over L*D*D/4 = 32768
    float4 a = ((const float4*)W0_w)[i];
    ushort4 o0; o0.x = f2bf(a.x); o0.y = f2bf(a.y); o0.z = f2bf(a.z); o0.w = f2bf(a.w);
    ((ushort4*)W0b)[i] = o0;
    float4 c = ((const float4*)Wr_w)[i];
    ushort4 o1; o1.x = f2bf(c.x); o1.y = f2bf(c.y); o1.z = f2bf(c.z); o1.w = f2bf(c.w);
    ((ushort4*)Wrb)[i] = o1;
}

// ---------------------------------------------------------------------------
// Kernel 4: big MFMA GEMM  y[b,m,d] = sum_k adjb[b,m,k] * xT[b,d,k]  (bf16 out)
// 64x64 tile, BK=64, 4 waves (2x2, each 32x32), grid 1024 -> 4 blocks/CU.
// ---------------------------------------------------------------------------
__global__ __launch_bounds__(256)
void big_mfma_kernel(const unsigned short* __restrict__ adjb,   // [B][N][N]
                     const unsigned short* __restrict__ xT,     // [B][D][N]
                     unsigned short* __restrict__ y) {          // [B][N][D]
    __shared__ unsigned short As[8 * 512];   // 8 frags (16m x 32k each)
    __shared__ unsigned short Bs[8 * 512];

    const int b    = blockIdx.z;
    const int n0   = blockIdx.x * 64;    // over D
    const int m0   = blockIdx.y * 64;    // over N
    const int t    = threadIdx.x;
    const int w    = t >> 6;
    const int lane = t & 63;
    const int lrow = lane & 15;
    const int lk   = (lane >> 4) * 8;

    const unsigned short* gA = adjb + (size_t)b * N * N + (size_t)(m0 + w * 16 + lrow) * N + lk;
    const unsigned short* gB = xT   + (size_t)b * D * N + (size_t)(n0 + w * 16 + lrow) * N + lk;

    f32x4 acc[2][2];
    const f32x4 zero = {0.f, 0.f, 0.f, 0.f};
    #pragma unroll
    for (int i = 0; i < 2; ++i)
        #pragma unroll
        for (int j = 0; j < 2; ++j) acc[i][j] = zero;

    for (int k0 = 0; k0 < N; k0 += 64) {
        __syncthreads();
        gload16(gA + k0,      &As[(w * 2 + 0) * 512]);
        gload16(gA + k0 + 32, &As[(w * 2 + 1) * 512]);
        gload16(gB + k0,      &Bs[(w * 2 + 0) * 512]);
        gload16(gB + k0 + 32, &Bs[(w * 2 + 1) * 512]);
        __syncthreads();
        #pragma unroll
        for (int kc = 0; kc < 2; ++kc) {
            bf16x8 a[2], bb[2];
            #pragma unroll
            for (int i = 0; i < 2; ++i)
                a[i] = *(const bf16x8*)&As[((((w & 1) * 2 + i) * 2) + kc) * 512 + lane * 8];
            #pragma unroll
            for (int j = 0; j < 2; ++j)
                bb[j] = *(const bf16x8*)&Bs[((((w >> 1) * 2 + j) * 2) + kc) * 512 + lane * 8];
            #pragma unroll
            for (int i = 0; i < 2; ++i)
                #pragma unroll
                for (int j = 0; j < 2; ++j)
                    acc[i][j] = __builtin_amdgcn_mfma_f32_16x16x32_bf16(
                        a[i], bb[j], acc[i][j], 0, 0, 0);
        }
    }

    // Epilogue: C/D layout col=lane&15, row=(lane>>4)*4+reg -> bf16 y
    unsigned short* yb = y + (size_t)b * N * D;
    const int col  = lane & 15;
    const int quad = lane >> 4;
    #pragma unroll
    for (int i = 0; i < 2; ++i) {
        const int mBase = m0 + (w & 1) * 32 + i * 16 + quad * 4;
        #pragma unroll
        for (int r = 0; r < 4; ++r) {
            const size_t rowOff = (size_t)(mBase + r) * D;
            #pragma unroll
            for (int j = 0; j < 2; ++j) {
                const int d = n0 + (w >> 1) * 32 + j * 16 + col;
                yb[rowOff + d] = f2bf(acc[i][j][r]);
            }
        }
    }
}

// ---------------------------------------------------------------------------
// Kernel 5: small fused GEMM over concat-K (512):
//   z[m,j] = sum_d y[m,d]*Wr[j,d] + sum_d x[m,d]*W0[j,d]
//   v = relu((z + b0[j] + br[j]*rowsum[m]) * rdenom[m])
//   non-final: xout[m][j]=bf16(v), xoutT[b][j][n]=bf16(v)
//   final:     out[m][j] = nodes[m][j] + v   (fp32)
// ---------------------------------------------------------------------------
__global__ __launch_bounds__(256)
void small_mfma_kernel(const unsigned short* __restrict__ y,    // [M][D] bf16
                       const unsigned short* __restrict__ x,    // [M][D] bf16
                       const unsigned short* __restrict__ Wrb,  // [D][D] bf16 (layer)
                       const unsigned short* __restrict__ W0b,  // [D][D] bf16 (layer)
                       const float* __restrict__ br,            // [D]
                       const float* __restrict__ b0,            // [D]
                       const float* __restrict__ rdenom,        // [M]
                       const float* __restrict__ rowsum,        // [M]
                       const float* __restrict__ nodes,         // final only
                       unsigned short* __restrict__ xout,       // non-final
                       unsigned short* __restrict__ xoutT,      // non-final
                       float* __restrict__ out) {               // final only
    __shared__ unsigned short As[8 * 512];
    __shared__ unsigned short Bs[8 * 512];

    const int n0   = blockIdx.x * 64;    // over D (output feature)
    const int m0   = blockIdx.y * 64;    // over M
    const int t    = threadIdx.x;
    const int w    = t >> 6;
    const int lane = t & 63;
    const int lrow = lane & 15;
    const int lk   = (lane >> 4) * 8;

    const size_t aRow = (size_t)(m0 + w * 16 + lrow) * D + lk;
    const size_t bRow = (size_t)(n0 + w * 16 + lrow) * D + lk;

    f32x4 acc[2][2];
    const f32x4 zero = {0.f, 0.f, 0.f, 0.f};
    #pragma unroll
    for (int i = 0; i < 2; ++i)
        #pragma unroll
        for (int j = 0; j < 2; ++j) acc[i][j] = zero;

    #pragma unroll
    for (int k0 = 0; k0 < 2 * D; k0 += 64) {
        const unsigned short* Ab = (k0 < D) ? y : x;
        const unsigned short* Bb = (k0 < D) ? Wrb : W0b;
        const int kk = k0 & (D - 1);
        __syncthreads();
        gload16(Ab + aRow + kk,      &As[(w * 2 + 0) * 512]);
        gload16(Ab + aRow + kk + 32, &As[(w * 2 + 1) * 512]);
        gload16(Bb + bRow + kk,      &Bs[(w * 2 + 0) * 512]);
        gload16(Bb + bRow + kk + 32, &Bs[(w * 2 + 1) * 512]);
        __syncthreads();
        #pragma unroll
        for (int kc = 0; kc < 2; ++kc) {
            bf16x8 a[2], bb[2];
            #pragma unroll
            for (int i = 0; i < 2; ++i)
                a[i] = *(const bf16x8*)&As[((((w & 1) * 2 + i) * 2) + kc) * 512 + lane * 8];
            #pragma unroll
            for (int j = 0; j < 2; ++j)
                bb[j] = *(const bf16x8*)&Bs[((((w >> 1) * 2 + j) * 2) + kc) * 512 + lane * 8];
            #pragma unroll
            for (int i = 0; i < 2; ++i)
                #pragma unroll
                for (int j = 0; j < 2; ++j)
                    acc[i][j] = __builtin_amdgcn_mfma_f32_16x16x32_bf16(
                        a[i], bb[j], acc[i][j], 0, 0, 0);
        }
    }

    const int col  = lane & 15;
    const int quad = lane >> 4;
    #pragma unroll
    for (int i = 0; i < 2; ++i) {
        const int mBase = m0 + (w & 1) * 32 + i * 16 + quad * 4;
        float rd[4], ss[4];
        #pragma unroll
        for (int r = 0; r < 4; ++r) {
            rd[r] = rdenom[mBase + r];
            ss[r] = rowsum[mBase + r];
        }
        #pragma unroll
        for (int j = 0; j < 2; ++j) {
            const int jj = n0 + (w >> 1) * 32 + j * 16 + col;
            const float bj = b0[jj];
            const float bv = br[jj];
            if (out) {
                #pragma unroll
                for (int r = 0; r < 4; ++r) {
                    const size_t idx = (size_t)(mBase + r) * D + jj;
                    float v = (acc[i][j][r] + bj + bv * ss[r]) * rd[r];
                    out[idx] = nodes[idx] + fmaxf(v, 0.f);
                }
            } else {
                ushort4 o;
                float v0 = fmaxf((acc[i][j][0] + bj + bv * ss[0]) * rd[0], 0.f);
                float v1 = fmaxf((acc[i][j][1] + bj + bv * ss[1]) * rd[1], 0.f);
                float v2 = fmaxf((acc[i][j][2] + bj + bv * ss[2]) * rd[2], 0.f);
                float v3 = fmaxf((acc[i][j][3] + bj + bv * ss[3]) * rd[3], 0.f);
                o.x = f2bf(v0); o.y = f2bf(v1); o.z = f2bf(v2); o.w = f2bf(v3);
                xout[(size_t)(mBase + 0) * D + jj] = o.x;
                xout[(size_t)(mBase + 1) * D + jj] = o.y;
                xout[(size_t)(mBase + 2) * D + jj] = o.z;
                xout[(size_t)(mBase + 3) * D + jj] = o.w;
                // transposed: [b][jj][nloc], 4 consecutive n -> vector store
                const int bb_ = m0 >> 11;            // batch (tile never crosses)
                const int nloc = mBase & (N - 1);
                *(ushort4*)&xoutT[((size_t)bb_ * D + jj) * N + nloc] = o;
            }
        }
    }
}

// ---------------------------------------------------------------------------
extern "C" void kernel_launch(void* const* d_in, const int* in_sizes, int n_in,
                              void* d_out, int out_size, void* d_ws, size_t ws_size,
                              hipStream_t stream) {
    const float* nodes = (const float*)d_in[0];   // [B,N,D]
    const float* adj   = (const float*)d_in[1];   // [B,N,N]
    const float* W0_w  = (const float*)d_in[2];   // [L,D,D]
    const float* W0_b  = (const float*)d_in[3];   // [L,D]
    const float* Wr_w  = (const float*)d_in[4];   // [L,D,D]
    const float* Wr_b  = (const float*)d_in[5];   // [L,D]
    float* out = (float*)d_out;

    // workspace carve (~101 MB)
    unsigned short* adjb    = (unsigned short*)d_ws;          // B*N*N
    unsigned short* xTbuf   = adjb  + (size_t)B * N * N;      // [B][D][N] (nodesT, then x1T)
    unsigned short* nodesbf = xTbuf + (size_t)B * D * N;      // [B][N][D]
    unsigned short* ybuf    = nodesbf + (size_t)B * N * D;    // [B][N][D]
    unsigned short* x1      = ybuf  + (size_t)B * N * D;      // [B][N][D]
    unsigned short* Wrb     = x1    + (size_t)B * N * D;      // L*D*D
    unsigned short* W0b     = Wrb   + (size_t)L * D * D;      // L*D*D
    float* rdenom = (float*)(W0b + (size_t)L * D * D);        // M
    float* rowsum = rdenom + M;                               // M

    denom_cast_kernel<<<dim3(B * N / 4), 256, 0, stream>>>(adj, adjb, rdenom, rowsum);
    cast_nodes_kernel<<<dim3(D / 64, N / 64, B), 256, 0, stream>>>(nodes, nodesbf, xTbuf);
    cast_w_kernel<<<dim3(L * D * D / 4 / 256), 256, 0, stream>>>(W0_w, Wr_w, W0b, Wrb);

    // layer 0
    big_mfma_kernel<<<dim3(D / 64, N / 64, B), 256, 0, stream>>>(adjb, xTbuf, ybuf);
    small_mfma_kernel<<<dim3(D / 64, M / 64), 256, 0, stream>>>(
        ybuf, nodesbf, Wrb, W0b, Wr_b, W0_b, rdenom, rowsum,
        nullptr, x1, xTbuf, nullptr);

    // layer 1
    big_mfma_kernel<<<dim3(D / 64, N / 64, B), 256, 0, stream>>>(adjb, xTbuf, ybuf);
    small_mfma_kernel<<<dim3(D / 64, M / 64), 256, 0, stream>>>(
        ybuf, x1, Wrb + D * D, W0b + D * D, Wr_b + D, W0_b + D, rdenom, rowsum,
        nodes, nullptr, nullptr, out);
}

// Round 4
// 362.263 us; speedup vs baseline: 2.3032x; 1.1146x over previous
//
#include <hip/hip_runtime.h>

// Problem constants
constexpr int B = 8;
constexpr int N = 2048;
constexpr int D = 256;
constexpr int L = 2;
constexpr int M = B * N;   // 16384

typedef __bf16 bf16x8 __attribute__((ext_vector_type(8)));
typedef float  f32x4  __attribute__((ext_vector_type(4)));

static __device__ __forceinline__ unsigned short f2bf(float f) {
    union { float f; unsigned u; } v; v.f = f;
    unsigned r = v.u + 0x7fffu + ((v.u >> 16) & 1u);   // RNE
    return (unsigned short)(r >> 16);
}

static __device__ __forceinline__ void gload16(const void* g, void* l) {
    __builtin_amdgcn_global_load_lds(
        (__attribute__((address_space(1))) void*)(g),
        (__attribute__((address_space(3))) void*)(l),
        16, 0, 0);
}

// ---------------------------------------------------------------------------
// Kernel 1: rowsum[b,n] = sum_k adj[b,n,k]; rdenom = 1/(rowsum+1); adj -> bf16.
// ---------------------------------------------------------------------------
__global__ __launch_bounds__(256)
void denom_cast_kernel(const float* __restrict__ adj,
                       unsigned short* __restrict__ adjb,
                       float* __restrict__ rdenom,
                       float* __restrict__ rowsum) {
    const int wave = threadIdx.x >> 6;
    const int lane = threadIdx.x & 63;
    const int row  = blockIdx.x * 4 + wave;          // [0, B*N)
    const float4* p = (const float4*)(adj + (size_t)row * N);
    ushort4* q = (ushort4*)(adjb + (size_t)row * N);
    float s = 0.f;
    #pragma unroll
    for (int i = 0; i < 8; ++i) {
        float4 v = p[lane + i * 64];
        s += (v.x + v.y) + (v.z + v.w);
        ushort4 o;
        o.x = f2bf(v.x); o.y = f2bf(v.y); o.z = f2bf(v.z); o.w = f2bf(v.w);
        q[lane + i * 64] = o;
    }
    #pragma unroll
    for (int off = 32; off > 0; off >>= 1) s += __shfl_down(s, off);
    if (lane == 0) {
        rowsum[row] = s;
        rdenom[row] = 1.0f / (s + 1.0f);
    }
}

// ---------------------------------------------------------------------------
// Kernel 2: nodes fp32 [b][n][d] -> nodesbf bf16 [b][n][d] AND nodesT [b][d][n].
// ---------------------------------------------------------------------------
__global__ __launch_bounds__(256)
void cast_nodes_kernel(const float* __restrict__ nodes,
                       unsigned short* __restrict__ nodesbf,
                       unsigned short* __restrict__ nodesT) {
    __shared__ unsigned short T[64][68];
    const int b  = blockIdx.z;
    const int n0 = blockIdx.y * 64;
    const int d0 = blockIdx.x * 64;
    const int t  = threadIdx.x;
    const int r  = t >> 2;                 // 0..63
    const int c4 = t & 3;                  // 0..3
    const float*    src = nodes   + ((size_t)b * N + n0) * D + d0;
    unsigned short* dst = nodesbf + ((size_t)b * N + n0) * D + d0;
    #pragma unroll
    for (int rep = 0; rep < 4; ++rep) {
        const int fc = c4 + rep * 4;
        float4 v = *(const float4*)(src + (size_t)r * D + fc * 4);
        ushort4 o;
        o.x = f2bf(v.x); o.y = f2bf(v.y); o.z = f2bf(v.z); o.w = f2bf(v.w);
        *(ushort4*)(dst + (size_t)r * D + fc * 4) = o;
        *(ushort4*)&T[r][fc * 4] = o;
    }
    __syncthreads();
    unsigned short* dstT = nodesT + ((size_t)b * D + d0) * N + n0;
    #pragma unroll
    for (int rep = 0; rep < 4; ++rep) {
        const int nc = c4 + rep * 4;
        ushort4 o;
        o.x = T[nc * 4 + 0][r];
        o.y = T[nc * 4 + 1][r];
        o.z = T[nc * 4 + 2][r];
        o.w = T[nc * 4 + 3][r];
        *(ushort4*)(dstT + (size_t)r * N + nc * 4) = o;
    }
}

// ---------------------------------------------------------------------------
// Kernel 3: cast both weight tensors [L][D][D] fp32 -> bf16.
// ---------------------------------------------------------------------------
__global__ __launch_bounds__(256)
void cast_w_kernel(const float* __restrict__ W0_w, const float* __restrict__ Wr_w,
                   unsigned short* __restrict__ W0b, unsigned short* __restrict__ Wrb) {
    const int i = blockIdx.x * 256 + threadIdx.x;
    float4 a = ((const float4*)W0_w)[i];
    ushort4 o0; o0.x = f2bf(a.x); o0.y = f2bf(a.y); o0.z = f2bf(a.z); o0.w = f2bf(a.w);
    ((ushort4*)W0b)[i] = o0;
    float4 c = ((const float4*)Wr_w)[i];
    ushort4 o1; o1.x = f2bf(c.x); o1.y = f2bf(c.y); o1.z = f2bf(c.z); o1.w = f2bf(c.w);
    ((ushort4*)Wrb)[i] = o1;
}

// ---------------------------------------------------------------------------
// Kernel 4: big MFMA GEMM  y[b,m,d] = sum_k adjb[b,m,k] * xT[b,d,k]  (bf16 out)
// 128(M)x64(N) tile, BK=64, 4 waves 2x2 (each 64m x 32n), grid 512 -> 2+/CU.
// A: 16 frags (8 mi x 2 kc), B: 8 frags (4 ni x 2 kc); 24 gload16/iter,
// 64 MFMA/iter -> 2.67 MFMA per staged frag.
// ---------------------------------------------------------------------------
__global__ __launch_bounds__(256)
void big_mfma_kernel(const unsigned short* __restrict__ adjb,   // [B][N][N]
                     const unsigned short* __restrict__ xT,     // [B][D][N]
                     unsigned short* __restrict__ y) {          // [B][N][D]
    __shared__ unsigned short As[16 * 512];   // 16 KB
    __shared__ unsigned short Bs[8 * 512];    //  8 KB

    const int b    = blockIdx.z;
    const int n0   = blockIdx.x * 64;    // over D
    const int m0   = blockIdx.y * 128;   // over N
    const int t    = threadIdx.x;
    const int w    = t >> 6;
    const int lane = t & 63;
    const int lrow = lane & 15;
    const int lk   = (lane >> 4) * 8;

    const unsigned short* Ab = adjb + (size_t)b * N * N;
    const unsigned short* Bb = xT   + (size_t)b * D * N;

    // wave w stages A frags mi={2w,2w+1} x kc={0,1}; B frags ni=w x kc={0,1}
    const unsigned short* gA0 = Ab + (size_t)(m0 + (2 * w + 0) * 16 + lrow) * N + lk;
    const unsigned short* gA1 = Ab + (size_t)(m0 + (2 * w + 1) * 16 + lrow) * N + lk;
    const unsigned short* gB  = Bb + (size_t)(n0 + w * 16 + lrow) * N + lk;

    f32x4 acc[4][2];
    const f32x4 zero = {0.f, 0.f, 0.f, 0.f};
    #pragma unroll
    for (int i = 0; i < 4; ++i)
        #pragma unroll
        for (int j = 0; j < 2; ++j) acc[i][j] = zero;

    for (int k0 = 0; k0 < N; k0 += 64) {
        __syncthreads();
        gload16(gA0 + k0,      &As[((2 * w + 0) * 2 + 0) * 512]);
        gload16(gA0 + k0 + 32, &As[((2 * w + 0) * 2 + 1) * 512]);
        gload16(gA1 + k0,      &As[((2 * w + 1) * 2 + 0) * 512]);
        gload16(gA1 + k0 + 32, &As[((2 * w + 1) * 2 + 1) * 512]);
        gload16(gB + k0,       &Bs[(w * 2 + 0) * 512]);
        gload16(gB + k0 + 32,  &Bs[(w * 2 + 1) * 512]);
        __syncthreads();
        #pragma unroll
        for (int kc = 0; kc < 2; ++kc) {
            bf16x8 a[4], bb[2];
            #pragma unroll
            for (int i = 0; i < 4; ++i) {
                const int mi = (w & 1) * 4 + i;
                a[i] = *(const bf16x8*)&As[(mi * 2 + kc) * 512 + lane * 8];
            }
            #pragma unroll
            for (int j = 0; j < 2; ++j) {
                const int ni = (w >> 1) * 2 + j;
                bb[j] = *(const bf16x8*)&Bs[(ni * 2 + kc) * 512 + lane * 8];
            }
            #pragma unroll
            for (int i = 0; i < 4; ++i)
                #pragma unroll
                for (int j = 0; j < 2; ++j)
                    acc[i][j] = __builtin_amdgcn_mfma_f32_16x16x32_bf16(
                        a[i], bb[j], acc[i][j], 0, 0, 0);
        }
    }

    // Epilogue: C/D layout col=lane&15, row=(lane>>4)*4+reg -> bf16 y
    unsigned short* yb = y + (size_t)b * N * D;
    const int col  = lane & 15;
    const int quad = lane >> 4;
    #pragma unroll
    for (int i = 0; i < 4; ++i) {
        const int mBase = m0 + (w & 1) * 64 + i * 16 + quad * 4;
        #pragma unroll
        for (int r = 0; r < 4; ++r) {
            const size_t rowOff = (size_t)(mBase + r) * D;
            #pragma unroll
            for (int j = 0; j < 2; ++j) {
                const int d = n0 + (w >> 1) * 32 + j * 16 + col;
                yb[rowOff + d] = f2bf(acc[i][j][r]);
            }
        }
    }
}

// ---------------------------------------------------------------------------
// Kernel 5: small fused GEMM over concat-K (512):
//   z[m,j] = sum_d y[m,d]*Wr[j,d] + sum_d x[m,d]*W0[j,d]
//   v = relu((z + b0[j] + br[j]*rowsum[m]) * rdenom[m])
//   non-final: xout[m][j]=bf16(v), xoutT[b][j][n]=bf16(v)
//   final:     out[m][j] = nodes[m][j] + v   (fp32)
// ---------------------------------------------------------------------------
__global__ __launch_bounds__(256)
void small_mfma_kernel(const unsigned short* __restrict__ y,    // [M][D] bf16
                       const unsigned short* __restrict__ x,    // [M][D] bf16
                       const unsigned short* __restrict__ Wrb,  // [D][D] bf16 (layer)
                       const unsigned short* __restrict__ W0b,  // [D][D] bf16 (layer)
                       const float* __restrict__ br,            // [D]
                       const float* __restrict__ b0,            // [D]
                       const float* __restrict__ rdenom,        // [M]
                       const float* __restrict__ rowsum,        // [M]
                       const float* __restrict__ nodes,         // final only
                       unsigned short* __restrict__ xout,       // non-final
                       unsigned short* __restrict__ xoutT,      // non-final
                       float* __restrict__ out) {               // final only
    __shared__ unsigned short As[8 * 512];
    __shared__ unsigned short Bs[8 * 512];

    const int n0   = blockIdx.x * 64;    // over D (output feature)
    const int m0   = blockIdx.y * 64;    // over M
    const int t    = threadIdx.x;
    const int w    = t >> 6;
    const int lane = t & 63;
    const int lrow = lane & 15;
    const int lk   = (lane >> 4) * 8;

    const size_t aRow = (size_t)(m0 + w * 16 + lrow) * D + lk;
    const size_t bRow = (size_t)(n0 + w * 16 + lrow) * D + lk;

    f32x4 acc[2][2];
    const f32x4 zero = {0.f, 0.f, 0.f, 0.f};
    #pragma unroll
    for (int i = 0; i < 2; ++i)
        #pragma unroll
        for (int j = 0; j < 2; ++j) acc[i][j] = zero;

    #pragma unroll
    for (int k0 = 0; k0 < 2 * D; k0 += 64) {
        const unsigned short* Ab = (k0 < D) ? y : x;
        const unsigned short* Bb = (k0 < D) ? Wrb : W0b;
        const int kk = k0 & (D - 1);
        __syncthreads();
        gload16(Ab + aRow + kk,      &As[(w * 2 + 0) * 512]);
        gload16(Ab + aRow + kk + 32, &As[(w * 2 + 1) * 512]);
        gload16(Bb + bRow + kk,      &Bs[(w * 2 + 0) * 512]);
        gload16(Bb + bRow + kk + 32, &Bs[(w * 2 + 1) * 512]);
        __syncthreads();
        #pragma unroll
        for (int kc = 0; kc < 2; ++kc) {
            bf16x8 a[2], bb[2];
            #pragma unroll
            for (int i = 0; i < 2; ++i)
                a[i] = *(const bf16x8*)&As[((((w & 1) * 2 + i) * 2) + kc) * 512 + lane * 8];
            #pragma unroll
            for (int j = 0; j < 2; ++j)
                bb[j] = *(const bf16x8*)&Bs[((((w >> 1) * 2 + j) * 2) + kc) * 512 + lane * 8];
            #pragma unroll
            for (int i = 0; i < 2; ++i)
                #pragma unroll
                for (int j = 0; j < 2; ++j)
                    acc[i][j] = __builtin_amdgcn_mfma_f32_16x16x32_bf16(
                        a[i], bb[j], acc[i][j], 0, 0, 0);
        }
    }

    const int col  = lane & 15;
    const int quad = lane >> 4;
    #pragma unroll
    for (int i = 0; i < 2; ++i) {
        const int mBase = m0 + (w & 1) * 32 + i * 16 + quad * 4;
        float rd[4], ss[4];
        #pragma unroll
        for (int r = 0; r < 4; ++r) {
            rd[r] = rdenom[mBase + r];
            ss[r] = rowsum[mBase + r];
        }
        #pragma unroll
        for (int j = 0; j < 2; ++j) {
            const int jj = n0 + (w >> 1) * 32 + j * 16 + col;
            const float bj = b0[jj];
            const float bv = br[jj];
            if (out) {
                #pragma unroll
                for (int r = 0; r < 4; ++r) {
                    const size_t idx = (size_t)(mBase + r) * D + jj;
                    float v = (acc[i][j][r] + bj + bv * ss[r]) * rd[r];
                    out[idx] = nodes[idx] + fmaxf(v, 0.f);
                }
            } else {
                ushort4 o;
                float v0 = fmaxf((acc[i][j][0] + bj + bv * ss[0]) * rd[0], 0.f);
                float v1 = fmaxf((acc[i][j][1] + bj + bv * ss[1]) * rd[1], 0.f);
                float v2 = fmaxf((acc[i][j][2] + bj + bv * ss[2]) * rd[2], 0.f);
                float v3 = fmaxf((acc[i][j][3] + bj + bv * ss[3]) * rd[3], 0.f);
                o.x = f2bf(v0); o.y = f2bf(v1); o.z = f2bf(v2); o.w = f2bf(v3);
                xout[(size_t)(mBase + 0) * D + jj] = o.x;
                xout[(size_t)(mBase + 1) * D + jj] = o.y;
                xout[(size_t)(mBase + 2) * D + jj] = o.z;
                xout[(size_t)(mBase + 3) * D + jj] = o.w;
                const int bb_ = m0 >> 11;            // batch (tile never crosses)
                const int nloc = mBase & (N - 1);
                *(ushort4*)&xoutT[((size_t)bb_ * D + jj) * N + nloc] = o;
            }
        }
    }
}

// ---------------------------------------------------------------------------
extern "C" void kernel_launch(void* const* d_in, const int* in_sizes, int n_in,
                              void* d_out, int out_size, void* d_ws, size_t ws_size,
                              hipStream_t stream) {
    const float* nodes = (const float*)d_in[0];   // [B,N,D]
    const float* adj   = (const float*)d_in[1];   // [B,N,N]
    const float* W0_w  = (const float*)d_in[2];   // [L,D,D]
    const float* W0_b  = (const float*)d_in[3];   // [L,D]
    const float* Wr_w  = (const float*)d_in[4];   // [L,D,D]
    const float* Wr_b  = (const float*)d_in[5];   // [L,D]
    float* out = (float*)d_out;

    unsigned short* adjb    = (unsigned short*)d_ws;          // B*N*N
    unsigned short* xTbuf   = adjb  + (size_t)B * N * N;      // [B][D][N]
    unsigned short* nodesbf = xTbuf + (size_t)B * D * N;      // [B][N][D]
    unsigned short* ybuf    = nodesbf + (size_t)B * N * D;    // [B][N][D]
    unsigned short* x1      = ybuf  + (size_t)B * N * D;      // [B][N][D]
    unsigned short* Wrb     = x1    + (size_t)B * N * D;      // L*D*D
    unsigned short* W0b     = Wrb   + (size_t)L * D * D;      // L*D*D
    float* rdenom = (float*)(W0b + (size_t)L * D * D);        // M
    float* rowsum = rdenom + M;                               // M

    denom_cast_kernel<<<dim3(B * N / 4), 256, 0, stream>>>(adj, adjb, rdenom, rowsum);
    cast_nodes_kernel<<<dim3(D / 64, N / 64, B), 256, 0, stream>>>(nodes, nodesbf, xTbuf);
    cast_w_kernel<<<dim3(L * D * D / 4 / 256), 256, 0, stream>>>(W0_w, Wr_w, W0b, Wrb);

    // layer 0
    big_mfma_kernel<<<dim3(D / 64, N / 128, B), 256, 0, stream>>>(adjb, xTbuf, ybuf);
    small_mfma_kernel<<<dim3(D / 64, M / 64), 256, 0, stream>>>(
        ybuf, nodesbf, Wrb, W0b, Wr_b, W0_b, rdenom, rowsum,
        nullptr, x1, xTbuf, nullptr);

    // layer 1
    big_mfma_kernel<<<dim3(D / 64, N / 128, B), 256, 0, stream>>>(adjb, xTbuf, ybuf);
    small_mfma_kernel<<<dim3(D / 64, M / 64), 256, 0, stream>>>(
        ybuf, x1, Wrb + D * D, W0b + D * D, Wr_b + D, W0_b + D, rdenom, rowsum,
        nodes, nullptr, nullptr, out);
}

// Round 5
// 341.545 us; speedup vs baseline: 2.4429x; 1.0607x over previous
//
#include <hip/hip_runtime.h>

// Problem constants
constexpr int B = 8;
constexpr int N = 2048;
constexpr int D = 256;
constexpr int L = 2;
constexpr int M = B * N;   // 16384

typedef __bf16 bf16x8 __attribute__((ext_vector_type(8)));
typedef float  f32x4  __attribute__((ext_vector_type(4)));

static __device__ __forceinline__ unsigned short f2bf(float f) {
    union { float f; unsigned u; } v; v.f = f;
    unsigned r = v.u + 0x7fffu + ((v.u >> 16) & 1u);   // RNE
    return (unsigned short)(r >> 16);
}

static __device__ __forceinline__ float bf2f(unsigned short u) {
    union { unsigned u; float f; } v; v.u = ((unsigned)u) << 16;
    return v.f;
}

static __device__ __forceinline__ void gload16(const void* g, void* l) {
    __builtin_amdgcn_global_load_lds(
        (__attribute__((address_space(1))) void*)(g),
        (__attribute__((address_space(3))) void*)(l),
        16, 0, 0);
}

// ---------------------------------------------------------------------------
// Kernel 1: rowsum[b,n] = sum_k adj[b,n,k]; rdenom = 1/(rowsum+1); adj -> bf16.
// ---------------------------------------------------------------------------
__global__ __launch_bounds__(256)
void denom_cast_kernel(const float* __restrict__ adj,
                       unsigned short* __restrict__ adjb,
                       float* __restrict__ rdenom,
                       float* __restrict__ rowsum) {
    const int wave = threadIdx.x >> 6;
    const int lane = threadIdx.x & 63;
    const int row  = blockIdx.x * 4 + wave;          // [0, B*N)
    const float4* p = (const float4*)(adj + (size_t)row * N);
    ushort4* q = (ushort4*)(adjb + (size_t)row * N);
    float s = 0.f;
    #pragma unroll
    for (int i = 0; i < 8; ++i) {
        float4 v = p[lane + i * 64];
        s += (v.x + v.y) + (v.z + v.w);
        ushort4 o;
        o.x = f2bf(v.x); o.y = f2bf(v.y); o.z = f2bf(v.z); o.w = f2bf(v.w);
        q[lane + i * 64] = o;
    }
    #pragma unroll
    for (int off = 32; off > 0; off >>= 1) s += __shfl_down(s, off);
    if (lane == 0) {
        rowsum[row] = s;
        rdenom[row] = 1.0f / (s + 1.0f);
    }
}

// ---------------------------------------------------------------------------
// Kernel 2: nodes fp32 [b][n][d] -> nodesbf bf16 [b][n][d] AND nodesT [b][d][n].
// ---------------------------------------------------------------------------
__global__ __launch_bounds__(256)
void cast_nodes_kernel(const float* __restrict__ nodes,
                       unsigned short* __restrict__ nodesbf,
                       unsigned short* __restrict__ nodesT) {
    __shared__ unsigned short T[64][68];
    const int b  = blockIdx.z;
    const int n0 = blockIdx.y * 64;
    const int d0 = blockIdx.x * 64;
    const int t  = threadIdx.x;
    const int r  = t >> 2;                 // 0..63
    const int c4 = t & 3;                  // 0..3
    const float*    src = nodes   + ((size_t)b * N + n0) * D + d0;
    unsigned short* dst = nodesbf + ((size_t)b * N + n0) * D + d0;
    #pragma unroll
    for (int rep = 0; rep < 4; ++rep) {
        const int fc = c4 + rep * 4;
        float4 v = *(const float4*)(src + (size_t)r * D + fc * 4);
        ushort4 o;
        o.x = f2bf(v.x); o.y = f2bf(v.y); o.z = f2bf(v.z); o.w = f2bf(v.w);
        *(ushort4*)(dst + (size_t)r * D + fc * 4) = o;
        *(ushort4*)&T[r][fc * 4] = o;
    }
    __syncthreads();
    unsigned short* dstT = nodesT + ((size_t)b * D + d0) * N + n0;
    #pragma unroll
    for (int rep = 0; rep < 4; ++rep) {
        const int nc = c4 + rep * 4;
        ushort4 o;
        o.x = T[nc * 4 + 0][r];
        o.y = T[nc * 4 + 1][r];
        o.z = T[nc * 4 + 2][r];
        o.w = T[nc * 4 + 3][r];
        *(ushort4*)(dstT + (size_t)r * N + nc * 4) = o;
    }
}

// ---------------------------------------------------------------------------
// Kernel 3: cast both weight tensors [L][D][D] fp32 -> bf16.
// ---------------------------------------------------------------------------
__global__ __launch_bounds__(256)
void cast_w_kernel(const float* __restrict__ W0_w, const float* __restrict__ Wr_w,
                   unsigned short* __restrict__ W0b, unsigned short* __restrict__ Wrb) {
    const int i = blockIdx.x * 256 + threadIdx.x;
    float4 a = ((const float4*)W0_w)[i];
    ushort4 o0; o0.x = f2bf(a.x); o0.y = f2bf(a.y); o0.z = f2bf(a.z); o0.w = f2bf(a.w);
    ((ushort4*)W0b)[i] = o0;
    float4 c = ((const float4*)Wr_w)[i];
    ushort4 o1; o1.x = f2bf(c.x); o1.y = f2bf(c.y); o1.z = f2bf(c.z); o1.w = f2bf(c.w);
    ((ushort4*)Wrb)[i] = o1;
}

// ---------------------------------------------------------------------------
// Kernel 4: big MFMA GEMM, split-K=2:
//   ypart[s][b*N+m][d] = sum_{k in half s} adjb[b,m,k] * xT[b,d,k]  (bf16 out)
// 128x128 tile, BK=64, 4 waves 2x2 (each 64x64, 4x4 frags -> 2.0 MFMA:ds_read),
// grid (2,16,16) = 512 blocks -> 2 blocks/CU, 8 waves/CU.
// ---------------------------------------------------------------------------
__global__ __launch_bounds__(256)
void big_mfma_kernel(const unsigned short* __restrict__ adjb,   // [B][N][N]
                     const unsigned short* __restrict__ xT,     // [B][D][N]
                     unsigned short* __restrict__ ypart) {      // [2][M][D]
    __shared__ unsigned short As[16 * 512];   // 16 KB
    __shared__ unsigned short Bs[16 * 512];   // 16 KB

    const int z     = blockIdx.z;
    const int b     = z & 7;
    const int split = z >> 3;
    const int n0    = blockIdx.x * 128;   // over D
    const int m0    = blockIdx.y * 128;   // over N
    const int t     = threadIdx.x;
    const int w     = t >> 6;
    const int lane  = t & 63;
    const int lrow  = lane & 15;
    const int lk    = (lane >> 4) * 8;
    const int kbase = split * (N / 2);

    const unsigned short* Ab = adjb + (size_t)b * N * N + kbase;
    const unsigned short* Bb = xT   + (size_t)b * D * N + kbase;

    // wave w stages A frags mi={2w,2w+1} x kc={0,1}; B frags ni={2w,2w+1} x kc={0,1}
    const unsigned short* gA0 = Ab + (size_t)(m0 + (2 * w + 0) * 16 + lrow) * N + lk;
    const unsigned short* gA1 = Ab + (size_t)(m0 + (2 * w + 1) * 16 + lrow) * N + lk;
    const unsigned short* gB0 = Bb + (size_t)(n0 + (2 * w + 0) * 16 + lrow) * N + lk;
    const unsigned short* gB1 = Bb + (size_t)(n0 + (2 * w + 1) * 16 + lrow) * N + lk;

    f32x4 acc[4][4];
    const f32x4 zero = {0.f, 0.f, 0.f, 0.f};
    #pragma unroll
    for (int i = 0; i < 4; ++i)
        #pragma unroll
        for (int j = 0; j < 4; ++j) acc[i][j] = zero;

    for (int k0 = 0; k0 < N / 2; k0 += 64) {
        __syncthreads();
        gload16(gA0 + k0,      &As[((2 * w + 0) * 2 + 0) * 512]);
        gload16(gA0 + k0 + 32, &As[((2 * w + 0) * 2 + 1) * 512]);
        gload16(gA1 + k0,      &As[((2 * w + 1) * 2 + 0) * 512]);
        gload16(gA1 + k0 + 32, &As[((2 * w + 1) * 2 + 1) * 512]);
        gload16(gB0 + k0,      &Bs[((2 * w + 0) * 2 + 0) * 512]);
        gload16(gB0 + k0 + 32, &Bs[((2 * w + 0) * 2 + 1) * 512]);
        gload16(gB1 + k0,      &Bs[((2 * w + 1) * 2 + 0) * 512]);
        gload16(gB1 + k0 + 32, &Bs[((2 * w + 1) * 2 + 1) * 512]);
        __syncthreads();
        #pragma unroll
        for (int kc = 0; kc < 2; ++kc) {
            bf16x8 a[4], bb[4];
            #pragma unroll
            for (int i = 0; i < 4; ++i)
                a[i] = *(const bf16x8*)&As[((((w & 1) * 4 + i) * 2) + kc) * 512 + lane * 8];
            #pragma unroll
            for (int j = 0; j < 4; ++j)
                bb[j] = *(const bf16x8*)&Bs[((((w >> 1) * 4 + j) * 2) + kc) * 512 + lane * 8];
            #pragma unroll
            for (int i = 0; i < 4; ++i)
                #pragma unroll
                for (int j = 0; j < 4; ++j)
                    acc[i][j] = __builtin_amdgcn_mfma_f32_16x16x32_bf16(
                        a[i], bb[j], acc[i][j], 0, 0, 0);
        }
    }

    // Epilogue: C/D layout col=lane&15, row=(lane>>4)*4+reg -> bf16 ypart
    unsigned short* yb = ypart + ((size_t)split * M + (size_t)b * N) * D;
    const int col  = lane & 15;
    const int quad = lane >> 4;
    #pragma unroll
    for (int i = 0; i < 4; ++i) {
        const int mBase = m0 + (w & 1) * 64 + i * 16 + quad * 4;
        #pragma unroll
        for (int r = 0; r < 4; ++r) {
            const size_t rowOff = (size_t)(mBase + r) * D;
            #pragma unroll
            for (int j = 0; j < 4; ++j) {
                const int d = n0 + (w >> 1) * 64 + j * 16 + col;
                yb[rowOff + d] = f2bf(acc[i][j][r]);
            }
        }
    }
}

// ---------------------------------------------------------------------------
// Kernel 5: small fused GEMM over concat-K (768 = y0|y1|x):
//   z[m,j] = sum_d (y0+y1)[m,d]*Wr[j,d] + sum_d x[m,d]*W0[j,d]
//   v = relu((z + b0[j] + br[j]*rowsum[m]) * rdenom[m])
//   non-final: xout[m][j]=bf16(v), xoutT[b][j][n]=bf16(v)
//   final:     out[m][j] = nodesbf[m][j] + v   (fp32)
// 128(M)x64(N) tile, BK=64, grid (4,128)=512.
// ---------------------------------------------------------------------------
__global__ __launch_bounds__(256)
void small_mfma_kernel(const unsigned short* __restrict__ y0,   // [M][D] bf16
                       const unsigned short* __restrict__ y1,   // [M][D] bf16
                       const unsigned short* __restrict__ x,    // [M][D] bf16
                       const unsigned short* __restrict__ Wrb,  // [D][D] bf16 (layer)
                       const unsigned short* __restrict__ W0b,  // [D][D] bf16 (layer)
                       const float* __restrict__ br,            // [D]
                       const float* __restrict__ b0,            // [D]
                       const float* __restrict__ rdenom,        // [M]
                       const float* __restrict__ rowsum,        // [M]
                       const unsigned short* __restrict__ nodesbf, // final only
                       unsigned short* __restrict__ xout,       // non-final
                       unsigned short* __restrict__ xoutT,      // non-final
                       float* __restrict__ out) {               // final only
    __shared__ unsigned short As[16 * 512];   // 16 KB
    __shared__ unsigned short Bs[8 * 512];    //  8 KB

    const int n0   = blockIdx.x * 64;    // over D (output feature)
    const int m0   = blockIdx.y * 128;   // over M
    const int t    = threadIdx.x;
    const int w    = t >> 6;
    const int lane = t & 63;
    const int lrow = lane & 15;
    const int lk   = (lane >> 4) * 8;

    const size_t aRow0 = (size_t)(m0 + (2 * w + 0) * 16 + lrow) * D + lk;
    const size_t aRow1 = (size_t)(m0 + (2 * w + 1) * 16 + lrow) * D + lk;
    const size_t bRow  = (size_t)(n0 + w * 16 + lrow) * D + lk;

    f32x4 acc[4][2];
    const f32x4 zero = {0.f, 0.f, 0.f, 0.f};
    #pragma unroll
    for (int i = 0; i < 4; ++i)
        #pragma unroll
        for (int j = 0; j < 2; ++j) acc[i][j] = zero;

    #pragma unroll
    for (int s = 0; s < 3; ++s) {
        const unsigned short* Asrc = (s == 0) ? y0 : (s == 1) ? y1 : x;
        const unsigned short* Bsrc = (s < 2) ? Wrb : W0b;
        #pragma unroll
        for (int kk = 0; kk < D; kk += 64) {
            __syncthreads();
            gload16(Asrc + aRow0 + kk,      &As[((2 * w + 0) * 2 + 0) * 512]);
            gload16(Asrc + aRow0 + kk + 32, &As[((2 * w + 0) * 2 + 1) * 512]);
            gload16(Asrc + aRow1 + kk,      &As[((2 * w + 1) * 2 + 0) * 512]);
            gload16(Asrc + aRow1 + kk + 32, &As[((2 * w + 1) * 2 + 1) * 512]);
            gload16(Bsrc + bRow + kk,       &Bs[(w * 2 + 0) * 512]);
            gload16(Bsrc + bRow + kk + 32,  &Bs[(w * 2 + 1) * 512]);
            __syncthreads();
            #pragma unroll
            for (int kc = 0; kc < 2; ++kc) {
                bf16x8 a[4], bb[2];
                #pragma unroll
                for (int i = 0; i < 4; ++i)
                    a[i] = *(const bf16x8*)&As[((((w & 1) * 4 + i) * 2) + kc) * 512 + lane * 8];
                #pragma unroll
                for (int j = 0; j < 2; ++j)
                    bb[j] = *(const bf16x8*)&Bs[((((w >> 1) * 2 + j) * 2) + kc) * 512 + lane * 8];
                #pragma unroll
                for (int i = 0; i < 4; ++i)
                    #pragma unroll
                    for (int j = 0; j < 2; ++j)
                        acc[i][j] = __builtin_amdgcn_mfma_f32_16x16x32_bf16(
                            a[i], bb[j], acc[i][j], 0, 0, 0);
            }
        }
    }

    const int col  = lane & 15;
    const int quad = lane >> 4;
    #pragma unroll
    for (int i = 0; i < 4; ++i) {
        const int mBase = m0 + (w & 1) * 64 + i * 16 + quad * 4;
        float rd[4], ss[4];
        #pragma unroll
        for (int r = 0; r < 4; ++r) {
            rd[r] = rdenom[mBase + r];
            ss[r] = rowsum[mBase + r];
        }
        #pragma unroll
        for (int j = 0; j < 2; ++j) {
            const int jj = n0 + (w >> 1) * 32 + j * 16 + col;
            const float bj = b0[jj];
            const float bv = br[jj];
            if (out) {
                #pragma unroll
                for (int r = 0; r < 4; ++r) {
                    const size_t idx = (size_t)(mBase + r) * D + jj;
                    float v = (acc[i][j][r] + bj + bv * ss[r]) * rd[r];
                    out[idx] = bf2f(nodesbf[idx]) + fmaxf(v, 0.f);
                }
            } else {
                ushort4 o;
                float v0 = fmaxf((acc[i][j][0] + bj + bv * ss[0]) * rd[0], 0.f);
                float v1 = fmaxf((acc[i][j][1] + bj + bv * ss[1]) * rd[1], 0.f);
                float v2 = fmaxf((acc[i][j][2] + bj + bv * ss[2]) * rd[2], 0.f);
                float v3 = fmaxf((acc[i][j][3] + bj + bv * ss[3]) * rd[3], 0.f);
                o.x = f2bf(v0); o.y = f2bf(v1); o.z = f2bf(v2); o.w = f2bf(v3);
                xout[(size_t)(mBase + 0) * D + jj] = o.x;
                xout[(size_t)(mBase + 1) * D + jj] = o.y;
                xout[(size_t)(mBase + 2) * D + jj] = o.z;
                xout[(size_t)(mBase + 3) * D + jj] = o.w;
                const int bb_ = m0 >> 11;            // batch (tile never crosses)
                const int nloc = mBase & (N - 1);
                *(ushort4*)&xoutT[((size_t)bb_ * D + jj) * N + nloc] = o;
            }
        }
    }
}

// ---------------------------------------------------------------------------
extern "C" void kernel_launch(void* const* d_in, const int* in_sizes, int n_in,
                              void* d_out, int out_size, void* d_ws, size_t ws_size,
                              hipStream_t stream) {
    const float* nodes = (const float*)d_in[0];   // [B,N,D]
    const float* adj   = (const float*)d_in[1];   // [B,N,N]
    const float* W0_w  = (const float*)d_in[2];   // [L,D,D]
    const float* W0_b  = (const float*)d_in[3];   // [L,D]
    const float* Wr_w  = (const float*)d_in[4];   // [L,D,D]
    const float* Wr_b  = (const float*)d_in[5];   // [L,D]
    float* out = (float*)d_out;

    unsigned short* adjb    = (unsigned short*)d_ws;          // B*N*N
    unsigned short* xTbuf   = adjb  + (size_t)B * N * N;      // [B][D][N]
    unsigned short* nodesbf = xTbuf + (size_t)B * D * N;      // [B][N][D]
    unsigned short* ybuf    = nodesbf + (size_t)B * N * D;    // [2][M][D]
    unsigned short* x1      = ybuf  + (size_t)2 * M * D;      // [M][D]
    unsigned short* Wrb     = x1    + (size_t)M * D;          // L*D*D
    unsigned short* W0b     = Wrb   + (size_t)L * D * D;      // L*D*D
    float* rdenom = (float*)(W0b + (size_t)L * D * D);        // M
    float* rowsum = rdenom + M;                               // M

    denom_cast_kernel<<<dim3(B * N / 4), 256, 0, stream>>>(adj, adjb, rdenom, rowsum);
    cast_nodes_kernel<<<dim3(D / 64, N / 64, B), 256, 0, stream>>>(nodes, nodesbf, xTbuf);
    cast_w_kernel<<<dim3(L * D * D / 4 / 256), 256, 0, stream>>>(W0_w, Wr_w, W0b, Wrb);

    unsigned short* y0 = ybuf;
    unsigned short* y1 = ybuf + (size_t)M * D;

    // layer 0
    big_mfma_kernel<<<dim3(D / 128, N / 128, 2 * B), 256, 0, stream>>>(adjb, xTbuf, ybuf);
    small_mfma_kernel<<<dim3(D / 64, M / 128), 256, 0, stream>>>(
        y0, y1, nodesbf, Wrb, W0b, Wr_b, W0_b, rdenom, rowsum,
        nullptr, x1, xTbuf, nullptr);

    // layer 1
    big_mfma_kernel<<<dim3(D / 128, N / 128, 2 * B), 256, 0, stream>>>(adjb, xTbuf, ybuf);
    small_mfma_kernel<<<dim3(D / 64, M / 128), 256, 0, stream>>>(
        y0, y1, x1, Wrb + D * D, W0b + D * D, Wr_b + D, W0_b + D, rdenom, rowsum,
        nodesbf, nullptr, nullptr, out);
}

// Round 6
// 318.696 us; speedup vs baseline: 2.6181x; 1.0717x over previous
//
#include <hip/hip_runtime.h>
#include <hip/hip_fp8.h>

// Problem constants
constexpr int B = 8;
constexpr int N = 2048;
constexpr int D = 256;
constexpr int L = 2;
constexpr int M = B * N;   // 16384

typedef __bf16 bf16x8 __attribute__((ext_vector_type(8)));
typedef float  f32x4  __attribute__((ext_vector_type(4)));

static __device__ __forceinline__ unsigned short f2bf(float f) {
    union { float f; unsigned u; } v; v.f = f;
    unsigned r = v.u + 0x7fffu + ((v.u >> 16) & 1u);   // RNE
    return (unsigned short)(r >> 16);
}

static __device__ __forceinline__ unsigned char f2fp8(float f) {
    __hip_fp8_e4m3 v(f);          // OCP e4m3fn on gfx950
    return (unsigned char)v.__x;
}

static __device__ __forceinline__ void gload16(const void* g, void* l) {
    __builtin_amdgcn_global_load_lds(
        (__attribute__((address_space(1))) void*)(g),
        (__attribute__((address_space(3))) void*)(l),
        16, 0, 0);
}

// ---------------------------------------------------------------------------
// Kernel 1 (merged prep): three block-ranges.
//  [0,4096):       denom+cast: rowsum/rdenom, adj fp32 -> adj8 (e4m3)
//  [4096,5120):    nodes -> nodesbf (bf16 row-major) + nodesT8 (fp8 [b][d][n])
//  [5120,5248):    weights fp32 -> bf16 (both, all layers)
// ---------------------------------------------------------------------------
__global__ __launch_bounds__(256)
void prep_kernel(const float* __restrict__ adj,
                 const float* __restrict__ nodes,
                 const float* __restrict__ W0_w, const float* __restrict__ Wr_w,
                 unsigned char* __restrict__ adj8,
                 float* __restrict__ rdenom, float* __restrict__ rowsum,
                 unsigned short* __restrict__ nodesbf,
                 unsigned char* __restrict__ nodesT8,
                 unsigned short* __restrict__ W0b, unsigned short* __restrict__ Wrb) {
    __shared__ unsigned char T8[64][68];
    const int bx = blockIdx.x;
    const int t  = threadIdx.x;
    if (bx < 4096) {
        // ---- denom + adj cast: one wave per row ----
        const int wave = t >> 6;
        const int lane = t & 63;
        const int row  = bx * 4 + wave;              // [0, B*N)
        const float4* p = (const float4*)(adj + (size_t)row * N);
        uchar4* q = (uchar4*)(adj8 + (size_t)row * N);
        float s = 0.f;
        #pragma unroll
        for (int i = 0; i < 8; ++i) {
            float4 v = p[lane + i * 64];
            s += (v.x + v.y) + (v.z + v.w);
            uchar4 o;
            o.x = f2fp8(v.x); o.y = f2fp8(v.y); o.z = f2fp8(v.z); o.w = f2fp8(v.w);
            q[lane + i * 64] = o;
        }
        #pragma unroll
        for (int off = 32; off > 0; off >>= 1) s += __shfl_down(s, off);
        if (lane == 0) {
            rowsum[row] = s;
            rdenom[row] = 1.0f / (s + 1.0f);
        }
    } else if (bx < 4096 + 1024) {
        // ---- nodes cast + transpose: 64x64 tile ----
        const int idx = bx - 4096;                   // [0,1024)
        const int b   = idx >> 7;
        const int rem = idx & 127;
        const int n0  = (rem >> 2) * 64;
        const int d0  = (rem & 3) * 64;
        const int r   = t >> 2;                      // 0..63
        const int c4  = t & 3;                       // 0..3
        const float*    src = nodes   + ((size_t)b * N + n0) * D + d0;
        unsigned short* dst = nodesbf + ((size_t)b * N + n0) * D + d0;
        #pragma unroll
        for (int rep = 0; rep < 4; ++rep) {
            const int fc = c4 + rep * 4;
            float4 v = *(const float4*)(src + (size_t)r * D + fc * 4);
            ushort4 o;
            o.x = f2bf(v.x); o.y = f2bf(v.y); o.z = f2bf(v.z); o.w = f2bf(v.w);
            *(ushort4*)(dst + (size_t)r * D + fc * 4) = o;
            uchar4 o8;
            o8.x = f2fp8(v.x); o8.y = f2fp8(v.y); o8.z = f2fp8(v.z); o8.w = f2fp8(v.w);
            *(uchar4*)&T8[r][fc * 4] = o8;
        }
        __syncthreads();
        unsigned char* dstT = nodesT8 + ((size_t)b * D + d0) * N + n0;
        #pragma unroll
        for (int rep = 0; rep < 4; ++rep) {
            const int nc = c4 + rep * 4;
            uchar4 o;
            o.x = T8[nc * 4 + 0][r];
            o.y = T8[nc * 4 + 1][r];
            o.z = T8[nc * 4 + 2][r];
            o.w = T8[nc * 4 + 3][r];
            *(uchar4*)(dstT + (size_t)r * N + nc * 4) = o;
        }
    } else {
        // ---- weight cast ----
        const int i = (bx - 5120) * 256 + t;         // over L*D*D/4 = 32768
        float4 a = ((const float4*)W0_w)[i];
        ushort4 o0; o0.x = f2bf(a.x); o0.y = f2bf(a.y); o0.z = f2bf(a.z); o0.w = f2bf(a.w);
        ((ushort4*)W0b)[i] = o0;
        float4 c = ((const float4*)Wr_w)[i];
        ushort4 o1; o1.x = f2bf(c.x); o1.y = f2bf(c.y); o1.z = f2bf(c.z); o1.w = f2bf(c.w);
        ((ushort4*)Wrb)[i] = o1;
    }
}

// ---------------------------------------------------------------------------
// Kernel 2: big MFMA GEMM (fp8 e4m3 x fp8 e4m3 -> fp32), split-K=2:
//   ypart[s][b*N+m][d] = sum_{k in half s} adj8[b,m,k] * xT8[b,d,k]  (bf16 out)
// 128x128 tile, BK=64, 4 waves 2x2 (each 64x64).
// LDS layout per 16-row group g (1024 B): addr = g*1024 + kchunk*256 + row*16
// (exactly gload16's base + lane*16 with row=lane&15, kchunk=lane>>4).
// MFMA frag (16x16x32_fp8_fp8, 8 fp8/lane): row=lane&15, k=(lane>>4)*8+j.
// ---------------------------------------------------------------------------
__global__ __launch_bounds__(256)
void big_mfma_kernel(const unsigned char* __restrict__ adj8,   // [B][N][N] fp8
                     const unsigned char* __restrict__ xT8,    // [B][D][N] fp8
                     unsigned short* __restrict__ ypart) {     // [2][M][D] bf16
    __shared__ __align__(16) unsigned char As[8 * 1024];   // 8 KB
    __shared__ __align__(16) unsigned char Bs[8 * 1024];   // 8 KB

    const int z     = blockIdx.z;
    const int b     = z & 7;
    const int split = z >> 3;
    const int n0    = blockIdx.x * 128;   // over D
    const int m0    = blockIdx.y * 128;   // over N
    const int t     = threadIdx.x;
    const int w     = t >> 6;
    const int lane  = t & 63;
    const int lrow  = lane & 15;
    const int lkc   = (lane >> 4) * 16;   // 16-B k-chunk per lane
    const int q     = lane >> 4;
    const int kbase = split * (N / 2);

    const unsigned char* Ab = adj8 + (size_t)b * N * N + kbase;
    const unsigned char* Bb = xT8  + (size_t)b * D * N + kbase;

    // wave w stages A row-groups {2w,2w+1} and B row-groups {2w,2w+1}
    const unsigned char* gA0 = Ab + (size_t)(m0 + (2 * w + 0) * 16 + lrow) * N + lkc;
    const unsigned char* gA1 = Ab + (size_t)(m0 + (2 * w + 1) * 16 + lrow) * N + lkc;
    const unsigned char* gB0 = Bb + (size_t)(n0 + (2 * w + 0) * 16 + lrow) * N + lkc;
    const unsigned char* gB1 = Bb + (size_t)(n0 + (2 * w + 1) * 16 + lrow) * N + lkc;

    f32x4 acc[4][4];
    const f32x4 zero = {0.f, 0.f, 0.f, 0.f};
    #pragma unroll
    for (int i = 0; i < 4; ++i)
        #pragma unroll
        for (int j = 0; j < 4; ++j) acc[i][j] = zero;

    for (int k0 = 0; k0 < N / 2; k0 += 64) {
        __syncthreads();
        gload16(gA0 + k0, &As[(2 * w + 0) * 1024]);
        gload16(gA1 + k0, &As[(2 * w + 1) * 1024]);
        gload16(gB0 + k0, &Bs[(2 * w + 0) * 1024]);
        gload16(gB1 + k0, &Bs[(2 * w + 1) * 1024]);
        __syncthreads();
        #pragma unroll
        for (int kc = 0; kc < 2; ++kc) {
            // within-group offset selecting (row, k=32*kc + q*8 .. +8)
            const int off = (2 * kc + (q >> 1)) * 256 + lrow * 16 + (q & 1) * 8;
            long long a[4], bb[4];
            #pragma unroll
            for (int i = 0; i < 4; ++i)
                a[i] = *(const long long*)&As[((w & 1) * 4 + i) * 1024 + off];
            #pragma unroll
            for (int j = 0; j < 4; ++j)
                bb[j] = *(const long long*)&Bs[((w >> 1) * 4 + j) * 1024 + off];
            #pragma unroll
            for (int i = 0; i < 4; ++i)
                #pragma unroll
                for (int j = 0; j < 4; ++j)
                    acc[i][j] = __builtin_amdgcn_mfma_f32_16x16x32_fp8_fp8(
                        a[i], bb[j], acc[i][j], 0, 0, 0);
        }
    }

    // Epilogue: C/D layout col=lane&15, row=(lane>>4)*4+reg -> bf16 ypart
    unsigned short* yb = ypart + ((size_t)split * M + (size_t)b * N) * D;
    const int col  = lane & 15;
    const int quad = lane >> 4;
    #pragma unroll
    for (int i = 0; i < 4; ++i) {
        const int mBase = m0 + (w & 1) * 64 + i * 16 + quad * 4;
        #pragma unroll
        for (int r = 0; r < 4; ++r) {
            const size_t rowOff = (size_t)(mBase + r) * D;
            #pragma unroll
            for (int j = 0; j < 4; ++j) {
                const int d = n0 + (w >> 1) * 64 + j * 16 + col;
                yb[rowOff + d] = f2bf(acc[i][j][r]);
            }
        }
    }
}

// ---------------------------------------------------------------------------
// Kernel 3: small fused GEMM over concat-K (768 = y0|y1|x), bf16:
//   z[m,j] = sum_d (y0+y1)[m,d]*Wr[j,d] + sum_d x[m,d]*W0[j,d]
//   v = relu((z + b0[j] + br[j]*rowsum[m]) * rdenom[m])
//   non-final: xout[m][j]=bf16(v), xoutT8[b][j][n]=fp8(v)
//   final:     out[m][j] = nodes_f32[m][j] + v   (fp32)
// ---------------------------------------------------------------------------
__global__ __launch_bounds__(256)
void small_mfma_kernel(const unsigned short* __restrict__ y0,   // [M][D] bf16
                       const unsigned short* __restrict__ y1,   // [M][D] bf16
                       const unsigned short* __restrict__ x,    // [M][D] bf16
                       const unsigned short* __restrict__ Wrb,  // [D][D] bf16 (layer)
                       const unsigned short* __restrict__ W0b,  // [D][D] bf16 (layer)
                       const float* __restrict__ br,            // [D]
                       const float* __restrict__ b0,            // [D]
                       const float* __restrict__ rdenom,        // [M]
                       const float* __restrict__ rowsum,        // [M]
                       const float* __restrict__ nodesf,        // final only (fp32)
                       unsigned short* __restrict__ xout,       // non-final (bf16)
                       unsigned char* __restrict__ xoutT8,      // non-final (fp8 T)
                       float* __restrict__ out) {               // final only
    __shared__ __align__(16) unsigned short As[16 * 512];   // 16 KB
    __shared__ __align__(16) unsigned short Bs[8 * 512];    //  8 KB

    const int n0   = blockIdx.x * 64;    // over D (output feature)
    const int m0   = blockIdx.y * 128;   // over M
    const int t    = threadIdx.x;
    const int w    = t >> 6;
    const int lane = t & 63;
    const int lrow = lane & 15;
    const int lk   = (lane >> 4) * 8;

    const size_t aRow0 = (size_t)(m0 + (2 * w + 0) * 16 + lrow) * D + lk;
    const size_t aRow1 = (size_t)(m0 + (2 * w + 1) * 16 + lrow) * D + lk;
    const size_t bRow  = (size_t)(n0 + w * 16 + lrow) * D + lk;

    f32x4 acc[4][2];
    const f32x4 zero = {0.f, 0.f, 0.f, 0.f};
    #pragma unroll
    for (int i = 0; i < 4; ++i)
        #pragma unroll
        for (int j = 0; j < 2; ++j) acc[i][j] = zero;

    #pragma unroll
    for (int s = 0; s < 3; ++s) {
        const unsigned short* Asrc = (s == 0) ? y0 : (s == 1) ? y1 : x;
        const unsigned short* Bsrc = (s < 2) ? Wrb : W0b;
        #pragma unroll
        for (int kk = 0; kk < D; kk += 64) {
            __syncthreads();
            gload16(Asrc + aRow0 + kk,      &As[((2 * w + 0) * 2 + 0) * 512]);
            gload16(Asrc + aRow0 + kk + 32, &As[((2 * w + 0) * 2 + 1) * 512]);
            gload16(Asrc + aRow1 + kk,      &As[((2 * w + 1) * 2 + 0) * 512]);
            gload16(Asrc + aRow1 + kk + 32, &As[((2 * w + 1) * 2 + 1) * 512]);
            gload16(Bsrc + bRow + kk,       &Bs[(w * 2 + 0) * 512]);
            gload16(Bsrc + bRow + kk + 32,  &Bs[(w * 2 + 1) * 512]);
            __syncthreads();
            #pragma unroll
            for (int kc = 0; kc < 2; ++kc) {
                bf16x8 a[4], bb[2];
                #pragma unroll
                for (int i = 0; i < 4; ++i)
                    a[i] = *(const bf16x8*)&As[((((w & 1) * 4 + i) * 2) + kc) * 512 + lane * 8];
                #pragma unroll
                for (int j = 0; j < 2; ++j)
                    bb[j] = *(const bf16x8*)&Bs[((((w >> 1) * 2 + j) * 2) + kc) * 512 + lane * 8];
                #pragma unroll
                for (int i = 0; i < 4; ++i)
                    #pragma unroll
                    for (int j = 0; j < 2; ++j)
                        acc[i][j] = __builtin_amdgcn_mfma_f32_16x16x32_bf16(
                            a[i], bb[j], acc[i][j], 0, 0, 0);
            }
        }
    }

    const int col  = lane & 15;
    const int quad = lane >> 4;
    #pragma unroll
    for (int i = 0; i < 4; ++i) {
        const int mBase = m0 + (w & 1) * 64 + i * 16 + quad * 4;
        float rd[4], ss[4];
        #pragma unroll
        for (int r = 0; r < 4; ++r) {
            rd[r] = rdenom[mBase + r];
            ss[r] = rowsum[mBase + r];
        }
        #pragma unroll
        for (int j = 0; j < 2; ++j) {
            const int jj = n0 + (w >> 1) * 32 + j * 16 + col;
            const float bj = b0[jj];
            const float bv = br[jj];
            if (out) {
                #pragma unroll
                for (int r = 0; r < 4; ++r) {
                    const size_t idx = (size_t)(mBase + r) * D + jj;
                    float v = (acc[i][j][r] + bj + bv * ss[r]) * rd[r];
                    out[idx] = nodesf[idx] + fmaxf(v, 0.f);
                }
            } else {
                float v0 = fmaxf((acc[i][j][0] + bj + bv * ss[0]) * rd[0], 0.f);
                float v1 = fmaxf((acc[i][j][1] + bj + bv * ss[1]) * rd[1], 0.f);
                float v2 = fmaxf((acc[i][j][2] + bj + bv * ss[2]) * rd[2], 0.f);
                float v3 = fmaxf((acc[i][j][3] + bj + bv * ss[3]) * rd[3], 0.f);
                xout[(size_t)(mBase + 0) * D + jj] = f2bf(v0);
                xout[(size_t)(mBase + 1) * D + jj] = f2bf(v1);
                xout[(size_t)(mBase + 2) * D + jj] = f2bf(v2);
                xout[(size_t)(mBase + 3) * D + jj] = f2bf(v3);
                // transposed fp8 for next layer's big GEMM B-operand
                uchar4 o8;
                o8.x = f2fp8(v0); o8.y = f2fp8(v1); o8.z = f2fp8(v2); o8.w = f2fp8(v3);
                const int bb_  = m0 >> 11;           // batch (tile never crosses)
                const int nloc = mBase & (N - 1);
                *(uchar4*)&xoutT8[((size_t)bb_ * D + jj) * N + nloc] = o8;
            }
        }
    }
}

// ---------------------------------------------------------------------------
extern "C" void kernel_launch(void* const* d_in, const int* in_sizes, int n_in,
                              void* d_out, int out_size, void* d_ws, size_t ws_size,
                              hipStream_t stream) {
    const float* nodes = (const float*)d_in[0];   // [B,N,D]
    const float* adj   = (const float*)d_in[1];   // [B,N,N]
    const float* W0_w  = (const float*)d_in[2];   // [L,D,D]
    const float* W0_b  = (const float*)d_in[3];   // [L,D]
    const float* Wr_w  = (const float*)d_in[4];   // [L,D,D]
    const float* Wr_b  = (const float*)d_in[5];   // [L,D]
    float* out = (float*)d_out;

    unsigned char*  adj8    = (unsigned char*)d_ws;           // B*N*N fp8 (33.5 MB)
    unsigned char*  xT8     = adj8 + (size_t)B * N * N;       // [B][D][N] fp8 (4.2 MB)
    unsigned short* nodesbf = (unsigned short*)(xT8 + (size_t)B * D * N);  // [M][D] bf16
    unsigned short* ybuf    = nodesbf + (size_t)M * D;        // [2][M][D] bf16
    unsigned short* x1      = ybuf + (size_t)2 * M * D;       // [M][D] bf16
    unsigned short* Wrb     = x1 + (size_t)M * D;             // L*D*D bf16
    unsigned short* W0b     = Wrb + (size_t)L * D * D;        // L*D*D bf16
    float* rdenom = (float*)(W0b + (size_t)L * D * D);        // M
    float* rowsum = rdenom + M;                               // M

    prep_kernel<<<dim3(5248), 256, 0, stream>>>(
        adj, nodes, W0_w, Wr_w,
        adj8, rdenom, rowsum, nodesbf, xT8, W0b, Wrb);

    unsigned short* y0 = ybuf;
    unsigned short* y1 = ybuf + (size_t)M * D;

    // layer 0
    big_mfma_kernel<<<dim3(D / 128, N / 128, 2 * B), 256, 0, stream>>>(adj8, xT8, ybuf);
    small_mfma_kernel<<<dim3(D / 64, M / 128), 256, 0, stream>>>(
        y0, y1, nodesbf, Wrb, W0b, Wr_b, W0_b, rdenom, rowsum,
        nullptr, x1, xT8, nullptr);

    // layer 1
    big_mfma_kernel<<<dim3(D / 128, N / 128, 2 * B), 256, 0, stream>>>(adj8, xT8, ybuf);
    small_mfma_kernel<<<dim3(D / 64, M / 128), 256, 0, stream>>>(
        y0, y1, x1, Wrb + D * D, W0b + D * D, Wr_b + D, W0_b + D, rdenom, rowsum,
        nodes, nullptr, nullptr, out);
}